// Round 6
// baseline (434.803 us; speedup 1.0000x reference)
//
#include <hip/hip_runtime.h>
#include <hip/hip_bf16.h>

#define BB 256
#define CC 1024
#define CQ 128
#define NN 196
#define TXTK 153600
#define SPLITS 64
#define KCHUNK 2400
#define KSTEPS 75
#define LDP 36  // padded LDS row stride in ushorts (72B: 18r mod 32 -> 16 distinct banks, <=2-way)

typedef __attribute__((ext_vector_type(8))) short short8;
typedef __attribute__((ext_vector_type(4))) float f32x4;

// packed f32x2 -> bf16x2 (compiler emits v_cvt_pk_bf16_f32; RNE)
static __device__ __forceinline__ unsigned int pkbf(float a, float b) {
  __hip_bfloat162 t = __float22bfloat162_rn(make_float2(a, b));
  unsigned int r;
  __builtin_memcpy(&r, &t, 4);
  return r;
}

// K1: split-K bf16 MFMA GEMM: partial[sp][b][c] = sum_{k in chunk} TE[b,k]*Gw[c,k]
// BM=256, BN=128, BK=32, 512 threads (8 waves, 4m x 2n, 64x64 per wave).
// 54 KB LDS + ~120 VGPR -> 2 blocks/CU: inter-block overlap hides the
// vmcnt(0)-before-barrier drain. Grid 512 = 8 nt x 64 sp, XCD-swizzled so the
// 8 nt-blocks sharing a TE k-chunk are co-resident on one XCD.
__global__ __launch_bounds__(512) void k1_gemm_partial(
    const float* __restrict__ TE, const float* __restrict__ Gw,
    float* __restrict__ part) {
  __shared__ unsigned short Al[2][256 * LDP];
  __shared__ unsigned short Bl[2][128 * LDP];

  const int tid = threadIdx.x;
  const int fid = blockIdx.x;            // 0..511
  const int spl = fid & 7;               // XCD under round-robin
  const int sph = (fid >> 3) & 7;
  const int nt = fid >> 6;               // 0..7 (c tile of 128)
  const int sp = sph * 8 + spl;          // 0..63 (k split); same sp -> same XCD
  const int kbase = sp * KCHUNK;

  const int lane = tid & 63;
  const int w = tid >> 6;      // 0..7
  const int wm = w & 3;        // 64-row band
  const int wn = w >> 2;       // 64-col band (0..1)

  // staging: A 256x32 f32 (4 chunks), B 128x32 f32 (2 chunks); 512 threads
  const int r0 = tid >> 3;           // 0..63
  const int c0 = (tid & 7) * 4;      // 0,4,..28
  int arow[4], brow[2];
#pragma unroll
  for (int j = 0; j < 4; ++j) arow[j] = r0 + 64 * j;
#pragma unroll
  for (int j = 0; j < 2; ++j) brow[j] = r0 + 64 * j;

  f32x4 ra[4], rb[2];
  auto loadRegs = [&](int ko) {
#pragma unroll
    for (int j = 0; j < 4; ++j)
      ra[j] = *(const f32x4*)(TE + (size_t)arow[j] * TXTK + kbase + ko + c0);
#pragma unroll
    for (int j = 0; j < 2; ++j)
      rb[j] = *(const f32x4*)(Gw + (size_t)(nt * 128 + brow[j]) * TXTK + kbase + ko + c0);
  };
  auto cvt4 = [](f32x4 v) {
    uint2 h;
    h.x = pkbf(v.x, v.y);
    h.y = pkbf(v.z, v.w);
    return h;
  };
  auto writeLDS = [&](int buf) {
#pragma unroll
    for (int j = 0; j < 4; ++j)
      *(uint2*)&Al[buf][arow[j] * LDP + c0] = cvt4(ra[j]);
#pragma unroll
    for (int j = 0; j < 2; ++j)
      *(uint2*)&Bl[buf][brow[j] * LDP + c0] = cvt4(rb[j]);
  };

  f32x4 acc[4][4];
  const f32x4 z = {0.f, 0.f, 0.f, 0.f};
#pragma unroll
  for (int i = 0; i < 4; ++i)
#pragma unroll
    for (int j = 0; j < 4; ++j) acc[i][j] = z;

  loadRegs(0);
  writeLDS(0);
  __syncthreads();

  const int k8 = (lane >> 4) * 8;
  const int fr = lane & 15;

  for (int ks = 0; ks < KSTEPS; ++ks) {
    const int cur = ks & 1;
    if (ks + 1 < KSTEPS) loadRegs((ks + 1) * 32);

    short8 bfr[4];
#pragma unroll
    for (int ns = 0; ns < 4; ++ns) {
      int col = wn * 64 + ns * 16 + fr;
      bfr[ns] = *(const short8*)&Bl[cur][col * LDP + k8];
    }
#pragma unroll
    for (int ms = 0; ms < 4; ++ms) {
      int row = wm * 64 + ms * 16 + fr;
      short8 af = *(const short8*)&Al[cur][row * LDP + k8];
#pragma unroll
      for (int ns = 0; ns < 4; ++ns)
        acc[ms][ns] = __builtin_amdgcn_mfma_f32_16x16x32_bf16(af, bfr[ns], acc[ms][ns], 0, 0, 0);
    }

    if (ks + 1 < KSTEPS) writeLDS(cur ^ 1);
    __syncthreads();
  }

  float* dst = part + (size_t)sp * (BB * CC);
#pragma unroll
  for (int ms = 0; ms < 4; ++ms)
#pragma unroll
    for (int ns = 0; ns < 4; ++ns)
#pragma unroll
      for (int j = 0; j < 4; ++j) {
        int b = wm * 64 + ms * 16 + (lane >> 4) * 4 + j;
        int c = nt * 128 + wn * 64 + ns * 16 + fr;
        dst[b * CC + c] = acc[ms][ns][j];
      }
}

// K2: te[b,c] = G_b[c] + sum_sp partial[sp][b][c]  (vectorized f32x4)
__global__ __launch_bounds__(256) void k2_reduce(
    const float* __restrict__ part, const float* __restrict__ Gb,
    float* __restrict__ te) {
  const int gid = blockIdx.x * 256 + threadIdx.x;  // 0..65535 (f32x4 units)
  const f32x4* p = (const f32x4*)part;
  f32x4 s = *(const f32x4*)(Gb + ((gid * 4) & (CC - 1)));
#pragma unroll 4
  for (int sp = 0; sp < SPLITS; ++sp) s += p[(size_t)sp * (BB * CC / 4) + gid];
  ((f32x4*)te)[gid] = s;
}

// K3 (fused dual): out[m,n] = sum_k te[m,k] * Wt[n,k]
// blockIdx.x < 2 -> Wk path (Nout=128); else Wv path (Nout=1024)
__global__ __launch_bounds__(256) void k3_dual(
    const float* __restrict__ te, const float* __restrict__ Wk,
    const float* __restrict__ Wv, float* __restrict__ kbuf,
    float* __restrict__ vbuf) {
  __shared__ float As[64][33];
  __shared__ float Bs[64][33];
  const int tid = threadIdx.x;
  const int tx = tid & 15, ty = tid >> 4;
  const int bx = blockIdx.x;
  const float* Wt;
  float* outp;
  int Nout, n0;
  if (bx < 2) { Wt = Wk; outp = kbuf; Nout = CQ; n0 = bx * 64; }
  else        { Wt = Wv; outp = vbuf; Nout = CC; n0 = (bx - 2) * 64; }
  const int m0 = blockIdx.y * 64;
  float acc[4][4] = {};
  for (int k0 = 0; k0 < CC; k0 += 32) {
#pragma unroll
    for (int j = 0; j < 2; ++j) {
      int i = tid + 256 * j;
      int r = i >> 3, c4 = (i & 7) * 4;
      f32x4 va = *(const f32x4*)(te + (size_t)(m0 + r) * CC + k0 + c4);
      As[r][c4 + 0] = va.x; As[r][c4 + 1] = va.y; As[r][c4 + 2] = va.z; As[r][c4 + 3] = va.w;
      f32x4 vb4 = *(const f32x4*)(Wt + (size_t)(n0 + r) * CC + k0 + c4);
      Bs[r][c4 + 0] = vb4.x; Bs[r][c4 + 1] = vb4.y; Bs[r][c4 + 2] = vb4.z; Bs[r][c4 + 3] = vb4.w;
    }
    __syncthreads();
#pragma unroll 8
    for (int k = 0; k < 32; ++k) {
      float a[4], bv[4];
#pragma unroll
      for (int i = 0; i < 4; ++i) a[i] = As[ty * 4 + i][k];
#pragma unroll
      for (int j = 0; j < 4; ++j) bv[j] = Bs[tx * 4 + j][k];
#pragma unroll
      for (int i = 0; i < 4; ++i)
#pragma unroll
        for (int j = 0; j < 4; ++j) acc[i][j] += a[i] * bv[j];
    }
    __syncthreads();
  }
#pragma unroll
  for (int i = 0; i < 4; ++i)
#pragma unroll
    for (int j = 0; j < 4; ++j)
      outp[(size_t)(m0 + ty * 4 + i) * Nout + n0 + tx * 4 + j] = acc[i][j];
}

// K4a: per (batch, channel-half): partial a[n] over 512 channels.
// h==0 partial also carries dsh = bq.kb. grid (2, 256), 1024 threads.
__global__ __launch_bounds__(1024) void k4a_attn(
    const float* __restrict__ x, const float* __restrict__ kb,
    const float* __restrict__ Wq, const float* __restrict__ bq,
    float* __restrict__ pbuf) {
  __shared__ float kbs[CQ];
  __shared__ float wqs[512];
  __shared__ float partl[16][NN];
  __shared__ float dsh;

  const int h = blockIdx.x;    // channel half
  const int b = blockIdx.y;    // batch
  const int ch0 = h * 512;
  const int tid = threadIdx.x;

  if (tid < CQ) kbs[tid] = kb[b * CQ + tid];
  __syncthreads();

  if (tid < 512) {
    float s = 0.f;
#pragma unroll 8
    for (int q = 0; q < CQ; ++q) s += Wq[q * CC + ch0 + tid] * kbs[q];
    wqs[tid] = s;
  }
  if (tid == 1023) {
    float d = 0.f;
    if (h == 0)
      for (int q = 0; q < CQ; ++q) d += bq[q] * kbs[q];
    dsh = d;
  }
  __syncthreads();

  const float* xb = x + (size_t)b * (CC * NN) + (size_t)ch0 * NN;
  if (tid < 784) {
    const int r = tid / 49, n4 = tid % 49;  // 16 rows x 49 quad-cols
    f32x4 acc = {0.f, 0.f, 0.f, 0.f};
#pragma unroll 4
    for (int c = r; c < 512; c += 16) {
      f32x4 v = *(const f32x4*)(xb + c * NN + n4 * 4);
      acc += wqs[c] * v;
    }
    partl[r][n4 * 4 + 0] = acc.x;
    partl[r][n4 * 4 + 1] = acc.y;
    partl[r][n4 * 4 + 2] = acc.z;
    partl[r][n4 * 4 + 3] = acc.w;
  }
  __syncthreads();
  if (tid < NN) {
    float s = dsh;
#pragma unroll
    for (int r = 0; r < 16; ++r) s += partl[r][tid];
    pbuf[b * 400 + h * 200 + tid] = s;
  }
}

// K4mid: a[n] = p0[n]+p1[n]; s[n] = sum_j l_j e^{a l_j} / sum_j e^{a l_j}
__global__ __launch_bounds__(256) void k4mid(
    const float* __restrict__ pbuf, const float* __restrict__ l,
    float* __restrict__ sbuf) {
  __shared__ float ls[NN];
  __shared__ float av[NN];
  const int b = blockIdx.x;
  const int tid = threadIdx.x;
  if (tid < NN) {
    ls[tid] = l[tid];
    av[tid] = pbuf[b * 400 + tid] + pbuf[b * 400 + 200 + tid];
  }
  __syncthreads();
  if (tid < NN) {
    const float a = av[tid];
    float m = -1e30f;
    for (int j = 0; j < NN; ++j) m = fmaxf(m, a * ls[j]);
    float num = 0.f, den = 0.f;
    for (int j = 0; j < NN; ++j) {
      float e = __expf(a * ls[j] - m);
      num += ls[j] * e;
      den += e;
    }
    sbuf[b * NN + tid] = num / den;
  }
}

// K4b: streaming epilogue: out[b,c,n] = g*vb[b,c]*s[b,n] + g*bv[c] + x[b,c,n]
__global__ __launch_bounds__(256) void k4b_epilogue(
    const float* __restrict__ x, const float* __restrict__ vbuf,
    const float* __restrict__ bv, const float* __restrict__ sbuf,
    const float* __restrict__ gammap, float* __restrict__ out) {
  __shared__ __align__(16) float sv[NN];
  __shared__ float Ac[128];
  __shared__ float Bc[128];
  const int sl = blockIdx.x;   // 0..7 (channel slice of 128)
  const int b = blockIdx.y;    // 0..255
  const int tid = threadIdx.x;
  const float g = gammap[0];

  if (tid < NN) sv[tid] = sbuf[b * NN + tid];
  if (tid < 128) {
    Ac[tid] = g * vbuf[b * CC + sl * 128 + tid];
    Bc[tid] = g * bv[sl * 128 + tid];
  }
  __syncthreads();

  const float* xb = x + (size_t)b * (CC * NN) + (size_t)sl * 128 * NN;
  float* ob = out + (size_t)b * (CC * NN) + (size_t)sl * 128 * NN;
  // 128 channels x 49 f32x4 chunks = 6272
  for (int f = tid; f < 6272; f += 256) {
    const int c = f / 49;
    const int n4 = f - c * 49;
    f32x4 xv = *(const f32x4*)(xb + f * 4);
    f32x4 s4 = *(const f32x4*)&sv[n4 * 4];
    f32x4 o = Ac[c] * s4 + (Bc[c] + xv);
    *(f32x4*)(ob + f * 4) = o;
  }
}

extern "C" void kernel_launch(void* const* d_in, const int* in_sizes, int n_in,
                              void* d_out, int out_size, void* d_ws, size_t ws_size,
                              hipStream_t stream) {
  const float* x    = (const float*)d_in[0];
  const float* TE   = (const float*)d_in[1];
  const float* Gw   = (const float*)d_in[2];
  const float* Gb   = (const float*)d_in[3];
  const float* l    = (const float*)d_in[4];
  const float* Wq   = (const float*)d_in[5];
  const float* bq   = (const float*)d_in[6];
  const float* Wk   = (const float*)d_in[7];
  // d_in[8] = b_k : cancels in the softmax (constant along the softmax axis)
  const float* Wv   = (const float*)d_in[9];
  const float* bv   = (const float*)d_in[10];
  const float* gam  = (const float*)d_in[11];

  float* out  = (float*)d_out;
  float* part = out;                 // 64*256*1024 floats (67 MB) scratch inside d_out
  float* pbuf = out + 20000000;      // 256*2*200 floats scratch (clear of part)
  float* te   = (float*)d_ws;        // 262144 floats
  float* kbuf = te + BB * CC;        // 32768
  float* vbuf = kbuf + BB * CQ;      // 262144
  float* sbuf = vbuf + BB * CC;      // 50176  (total ws use: ~2.4 MB)

  hipLaunchKernelGGL(k1_gemm_partial, dim3(512), dim3(512), 0, stream, TE, Gw, part);
  hipLaunchKernelGGL(k2_reduce, dim3(256), dim3(256), 0, stream, part, Gb, te);
  hipLaunchKernelGGL(k3_dual, dim3(18, 4), dim3(256), 0, stream, te, Wk, Wv, kbuf, vbuf);
  hipLaunchKernelGGL(k4a_attn, dim3(2, BB), dim3(1024), 0, stream, x, kbuf, Wq, bq, pbuf);
  hipLaunchKernelGGL(k4mid, dim3(BB), dim3(256), 0, stream, pbuf, l, sbuf);
  hipLaunchKernelGGL(k4b_epilogue, dim3(8, BB), dim3(256), 0, stream, x, vbuf, bv, sbuf, gam, out);
}

// Round 7
// 388.732 us; speedup vs baseline: 1.1185x; 1.1185x over previous
//
#include <hip/hip_runtime.h>
#include <hip/hip_bf16.h>

#define BB 256
#define CC 1024
#define CQ 128
#define NN 196
#define TXTK 153600
#define SPLITS 64
#define KCHUNK 2400
#define KSTEPS 75
#define LDP 40  // padded LDS row stride in ushorts (80B: rows r,r+8 alias -> 2-way, free)

typedef __attribute__((ext_vector_type(8))) short short8;
typedef __attribute__((ext_vector_type(4))) float f32x4;
typedef __attribute__((ext_vector_type(2))) unsigned int u32x2;

// packed f32x2 -> bf16x2 (compiler emits v_cvt_pk_bf16_f32; RNE)
static __device__ __forceinline__ unsigned int pkbf(float a, float b) {
  __hip_bfloat162 t = __float22bfloat162_rn(make_float2(a, b));
  unsigned int r;
  __builtin_memcpy(&r, &t, 4);
  return r;
}

static __device__ __forceinline__ float bflo(unsigned int u) {
  unsigned int v = u << 16;
  float f;
  __builtin_memcpy(&f, &v, 4);
  return f;
}
static __device__ __forceinline__ float bfhi(unsigned int u) {
  unsigned int v = u & 0xffff0000u;
  float f;
  __builtin_memcpy(&f, &v, 4);
  return f;
}

// K1: split-K bf16 MFMA GEMM: partial for te[b,c] = sum_k TE[b,k]*Gw[c,k]
// BM=256, BN=256, BK=32, 1024 threads (16 waves, 4m x 4n, 64x64 per wave).
// Partial stored as packed bf16 pairs in a block-private slot layout
// (coalesced u32x2 stores); K2 inverts the layout.
__global__ __launch_bounds__(1024) void k1_gemm_partial(
    const float* __restrict__ TE, const float* __restrict__ Gw,
    unsigned int* __restrict__ part) {
  __shared__ unsigned short Al[2][256 * LDP];
  __shared__ unsigned short Bl[2][256 * LDP];

  const int tid = threadIdx.x;
  const int fid = blockIdx.x;          // 0..255
  const int r8 = fid & 7;              // XCD under round-robin
  const int nt = (fid >> 3) & 3;       // c tile of 256
  const int sp = (fid >> 5) * 8 + r8;  // 0..63 (k split); same sp -> same XCD
  const int kbase = sp * KCHUNK;

  const int lane = tid & 63;
  const int w = tid >> 6;      // 0..15
  const int wm = w & 3;        // 64-row band
  const int wn = w >> 2;       // 64-col band

  // staging: 256x32 f32 each of A,B; 1024 threads x 2 chunks x f32x4
  const int r0 = tid >> 3;           // 0..127
  const int c0 = (tid & 7) * 4;      // 0,4,..28
  const float* Ap0 = TE + (size_t)r0 * TXTK + kbase + c0;
  const float* Ap1 = TE + (size_t)(r0 + 128) * TXTK + kbase + c0;
  const float* Bp0 = Gw + (size_t)(nt * 256 + r0) * TXTK + kbase + c0;
  const float* Bp1 = Gw + (size_t)(nt * 256 + r0 + 128) * TXTK + kbase + c0;
  const int l0 = r0 * LDP + c0;
  const int l1 = (r0 + 128) * LDP + c0;

  f32x4 ra0, ra1, rb0, rb1;
  auto loadRegs = [&](int ko) {
    ra0 = *(const f32x4*)(Ap0 + ko);
    ra1 = *(const f32x4*)(Ap1 + ko);
    rb0 = __builtin_nontemporal_load((const f32x4*)(Bp0 + ko));  // Gw: no reuse
    rb1 = __builtin_nontemporal_load((const f32x4*)(Bp1 + ko));
  };
  auto cvt4 = [](f32x4 v) {
    uint2 h;
    h.x = pkbf(v.x, v.y);
    h.y = pkbf(v.z, v.w);
    return h;
  };
  auto writeLDS = [&](int buf) {
    *(uint2*)&Al[buf][l0] = cvt4(ra0);
    *(uint2*)&Al[buf][l1] = cvt4(ra1);
    *(uint2*)&Bl[buf][l0] = cvt4(rb0);
    *(uint2*)&Bl[buf][l1] = cvt4(rb1);
  };

  f32x4 acc[4][4];
  const f32x4 z = {0.f, 0.f, 0.f, 0.f};
#pragma unroll
  for (int i = 0; i < 4; ++i)
#pragma unroll
    for (int j = 0; j < 4; ++j) acc[i][j] = z;

  loadRegs(0);
  writeLDS(0);
  __syncthreads();

  const int k8 = (lane >> 4) * 8;
  const int fr = lane & 15;

  for (int ks = 0; ks < KSTEPS; ++ks) {
    const int cur = ks & 1;
    if (ks + 1 < KSTEPS) loadRegs((ks + 1) * 32);

    short8 bfr[4];
#pragma unroll
    for (int ns = 0; ns < 4; ++ns) {
      int col = wn * 64 + ns * 16 + fr;
      bfr[ns] = *(const short8*)&Bl[cur][col * LDP + k8];
    }
#pragma unroll
    for (int ms = 0; ms < 4; ++ms) {
      int row = wm * 64 + ms * 16 + fr;
      short8 af = *(const short8*)&Al[cur][row * LDP + k8];
#pragma unroll
      for (int ns = 0; ns < 4; ++ns)
        acc[ms][ns] = __builtin_amdgcn_mfma_f32_16x16x32_bf16(af, bfr[ns], acc[ms][ns], 0, 0, 0);
    }

    if (ks + 1 < KSTEPS) writeLDS(cur ^ 1);
    __syncthreads();
  }

  // epilogue: pack 16 f32x4 -> 16 u32x2, coalesced block-private layout
  u32x2* d2 = (u32x2*)part + (size_t)(sp * 4 + nt) * 16384;
#pragma unroll
  for (int ms = 0; ms < 4; ++ms)
#pragma unroll
    for (int ns = 0; ns < 4; ++ns) {
      u32x2 pk;
      pk.x = pkbf(acc[ms][ns][0], acc[ms][ns][1]);
      pk.y = pkbf(acc[ms][ns][2], acc[ms][ns][3]);
      const int v = ms * 4 + ns;
      __builtin_nontemporal_store(pk, d2 + v * 1024 + tid);
    }
}

// K2: te[b,c] = G_b[c] + sum_sp partial; inverts K1's slot layout.
// idx -> (nt, v, t) -> (b,c); each thread handles one u32x2 = 4 outputs.
__global__ __launch_bounds__(1024) void k2_reduce(
    const unsigned int* __restrict__ part, const float* __restrict__ Gb,
    float* __restrict__ te) {
  const int idx = blockIdx.x * 1024 + threadIdx.x;  // 0..65535
  const int nt = idx >> 14;
  const int s = idx & 16383;            // v*1024 + t
  const u32x2* p2 = (const u32x2*)part;

  float a0 = 0.f, a1 = 0.f, a2 = 0.f, a3 = 0.f;
#pragma unroll 4
  for (int sp = 0; sp < SPLITS; ++sp) {
    u32x2 u = p2[(size_t)(sp * 4 + nt) * 16384 + s];
    a0 += bflo(u.x); a1 += bfhi(u.x);
    a2 += bflo(u.y); a3 += bfhi(u.y);
  }

  const int v = s >> 10, t = s & 1023;
  const int lane = t & 63, w = t >> 6;
  const int wm = w & 3, wn = w >> 2;
  const int ms = v >> 2, ns = v & 3;
  const int b0 = wm * 64 + ms * 16 + (lane >> 4) * 4;
  const int c = nt * 256 + wn * 64 + ns * 16 + (lane & 15);
  const float gb = Gb[c];
  te[(size_t)(b0 + 0) * CC + c] = a0 + gb;
  te[(size_t)(b0 + 1) * CC + c] = a1 + gb;
  te[(size_t)(b0 + 2) * CC + c] = a2 + gb;
  te[(size_t)(b0 + 3) * CC + c] = a3 + gb;
}

// K3 (fused dual): out[m,n] = sum_k te[m,k] * Wt[n,k]
// blockIdx.x < 2 -> Wk path (Nout=128); else Wv path (Nout=1024)
__global__ __launch_bounds__(256) void k3_dual(
    const float* __restrict__ te, const float* __restrict__ Wk,
    const float* __restrict__ Wv, float* __restrict__ kbuf,
    float* __restrict__ vbuf) {
  __shared__ float As[64][33];
  __shared__ float Bs[64][33];
  const int tid = threadIdx.x;
  const int tx = tid & 15, ty = tid >> 4;
  const int bx = blockIdx.x;
  const float* Wt;
  float* outp;
  int Nout, n0;
  if (bx < 2) { Wt = Wk; outp = kbuf; Nout = CQ; n0 = bx * 64; }
  else        { Wt = Wv; outp = vbuf; Nout = CC; n0 = (bx - 2) * 64; }
  const int m0 = blockIdx.y * 64;
  float acc[4][4] = {};
  for (int k0 = 0; k0 < CC; k0 += 32) {
#pragma unroll
    for (int j = 0; j < 2; ++j) {
      int i = tid + 256 * j;
      int r = i >> 3, c4 = (i & 7) * 4;
      f32x4 va = *(const f32x4*)(te + (size_t)(m0 + r) * CC + k0 + c4);
      As[r][c4 + 0] = va.x; As[r][c4 + 1] = va.y; As[r][c4 + 2] = va.z; As[r][c4 + 3] = va.w;
      f32x4 vb4 = *(const f32x4*)(Wt + (size_t)(n0 + r) * CC + k0 + c4);
      Bs[r][c4 + 0] = vb4.x; Bs[r][c4 + 1] = vb4.y; Bs[r][c4 + 2] = vb4.z; Bs[r][c4 + 3] = vb4.w;
    }
    __syncthreads();
#pragma unroll 8
    for (int k = 0; k < 32; ++k) {
      float a[4], bv[4];
#pragma unroll
      for (int i = 0; i < 4; ++i) a[i] = As[ty * 4 + i][k];
#pragma unroll
      for (int j = 0; j < 4; ++j) bv[j] = Bs[tx * 4 + j][k];
#pragma unroll
      for (int i = 0; i < 4; ++i)
#pragma unroll
        for (int j = 0; j < 4; ++j) acc[i][j] += a[i] * bv[j];
    }
    __syncthreads();
  }
#pragma unroll
  for (int i = 0; i < 4; ++i)
#pragma unroll
    for (int j = 0; j < 4; ++j)
      outp[(size_t)(m0 + ty * 4 + i) * Nout + n0 + tx * 4 + j] = acc[i][j];
}

// K4a: per (batch, channel-half): partial a[n] over 512 channels.
// h==0 partial also carries dsh = bq.kb. grid (2, 256), 1024 threads.
__global__ __launch_bounds__(1024) void k4a_attn(
    const float* __restrict__ x, const float* __restrict__ kb,
    const float* __restrict__ Wq, const float* __restrict__ bq,
    float* __restrict__ pbuf) {
  __shared__ float kbs[CQ];
  __shared__ float wqs[512];
  __shared__ float partl[16][NN];
  __shared__ float dsh;

  const int h = blockIdx.x;    // channel half
  const int b = blockIdx.y;    // batch
  const int ch0 = h * 512;
  const int tid = threadIdx.x;

  if (tid < CQ) kbs[tid] = kb[b * CQ + tid];
  __syncthreads();

  if (tid < 512) {
    float s = 0.f;
#pragma unroll 8
    for (int q = 0; q < CQ; ++q) s += Wq[q * CC + ch0 + tid] * kbs[q];
    wqs[tid] = s;
  }
  if (tid == 1023) {
    float d = 0.f;
    if (h == 0)
      for (int q = 0; q < CQ; ++q) d += bq[q] * kbs[q];
    dsh = d;
  }
  __syncthreads();

  const float* xb = x + (size_t)b * (CC * NN) + (size_t)ch0 * NN;
  if (tid < 784) {
    const int r = tid / 49, n4 = tid % 49;  // 16 rows x 49 quad-cols
    f32x4 acc = {0.f, 0.f, 0.f, 0.f};
#pragma unroll 4
    for (int c = r; c < 512; c += 16) {
      f32x4 v = *(const f32x4*)(xb + c * NN + n4 * 4);
      acc += wqs[c] * v;
    }
    partl[r][n4 * 4 + 0] = acc.x;
    partl[r][n4 * 4 + 1] = acc.y;
    partl[r][n4 * 4 + 2] = acc.z;
    partl[r][n4 * 4 + 3] = acc.w;
  }
  __syncthreads();
  if (tid < NN) {
    float s = dsh;
#pragma unroll
    for (int r = 0; r < 16; ++r) s += partl[r][tid];
    pbuf[b * 400 + h * 200 + tid] = s;
  }
}

// K4mid: a[n] = p0[n]+p1[n]; s[n] = sum_j l_j e^{a l_j} / sum_j e^{a l_j}
__global__ __launch_bounds__(256) void k4mid(
    const float* __restrict__ pbuf, const float* __restrict__ l,
    float* __restrict__ sbuf) {
  __shared__ float ls[NN];
  __shared__ float av[NN];
  const int b = blockIdx.x;
  const int tid = threadIdx.x;
  if (tid < NN) {
    ls[tid] = l[tid];
    av[tid] = pbuf[b * 400 + tid] + pbuf[b * 400 + 200 + tid];
  }
  __syncthreads();
  if (tid < NN) {
    const float a = av[tid];
    float m = -1e30f;
    for (int j = 0; j < NN; ++j) m = fmaxf(m, a * ls[j]);
    float num = 0.f, den = 0.f;
    for (int j = 0; j < NN; ++j) {
      float e = __expf(a * ls[j] - m);
      num += ls[j] * e;
      den += e;
    }
    sbuf[b * NN + tid] = num / den;
  }
}

// K4b: streaming epilogue: out[b,c,n] = g*vb[b,c]*s[b,n] + g*bv[c] + x[b,c,n]
__global__ __launch_bounds__(256) void k4b_epilogue(
    const float* __restrict__ x, const float* __restrict__ vbuf,
    const float* __restrict__ bv, const float* __restrict__ sbuf,
    const float* __restrict__ gammap, float* __restrict__ out) {
  __shared__ __align__(16) float sv[NN];
  __shared__ float Ac[128];
  __shared__ float Bc[128];
  const int sl = blockIdx.x;   // 0..7 (channel slice of 128)
  const int b = blockIdx.y;    // 0..255
  const int tid = threadIdx.x;
  const float g = gammap[0];

  if (tid < NN) sv[tid] = sbuf[b * NN + tid];
  if (tid < 128) {
    Ac[tid] = g * vbuf[b * CC + sl * 128 + tid];
    Bc[tid] = g * bv[sl * 128 + tid];
  }
  __syncthreads();

  const float* xb = x + (size_t)b * (CC * NN) + (size_t)sl * 128 * NN;
  float* ob = out + (size_t)b * (CC * NN) + (size_t)sl * 128 * NN;
  // 128 channels x 49 f32x4 chunks = 6272
  for (int f = tid; f < 6272; f += 256) {
    const int c = f / 49;
    const int n4 = f - c * 49;
    f32x4 xv = *(const f32x4*)(xb + f * 4);
    f32x4 s4 = *(const f32x4*)&sv[n4 * 4];
    f32x4 o = Ac[c] * s4 + (Bc[c] + xv);
    __builtin_nontemporal_store(o, (f32x4*)(ob + f * 4));
  }
}

extern "C" void kernel_launch(void* const* d_in, const int* in_sizes, int n_in,
                              void* d_out, int out_size, void* d_ws, size_t ws_size,
                              hipStream_t stream) {
  const float* x    = (const float*)d_in[0];
  const float* TE   = (const float*)d_in[1];
  const float* Gw   = (const float*)d_in[2];
  const float* Gb   = (const float*)d_in[3];
  const float* l    = (const float*)d_in[4];
  const float* Wq   = (const float*)d_in[5];
  const float* bq   = (const float*)d_in[6];
  const float* Wk   = (const float*)d_in[7];
  // d_in[8] = b_k : cancels in the softmax (constant along the softmax axis)
  const float* Wv   = (const float*)d_in[9];
  const float* bv   = (const float*)d_in[10];
  const float* gam  = (const float*)d_in[11];

  float* out  = (float*)d_out;
  unsigned int* part = (unsigned int*)d_out;  // 256 regions x 32768 uints = 33.5 MB
  float* pbuf = out + 20000000;      // 256*2*200 floats scratch (clear of part)
  float* te   = (float*)d_ws;        // 262144 floats
  float* kbuf = te + BB * CC;        // 32768
  float* vbuf = kbuf + BB * CQ;      // 262144
  float* sbuf = vbuf + BB * CC;      // 50176  (total ws use: ~2.4 MB)

  hipLaunchKernelGGL(k1_gemm_partial, dim3(256), dim3(1024), 0, stream, TE, Gw, part);
  hipLaunchKernelGGL(k2_reduce, dim3(64), dim3(1024), 0, stream, part, Gb, te);
  hipLaunchKernelGGL(k3_dual, dim3(18, 4), dim3(256), 0, stream, te, Wk, Wv, kbuf, vbuf);
  hipLaunchKernelGGL(k4a_attn, dim3(2, BB), dim3(1024), 0, stream, x, kbuf, Wq, bq, pbuf);
  hipLaunchKernelGGL(k4mid, dim3(BB), dim3(256), 0, stream, pbuf, l, sbuf);
  hipLaunchKernelGGL(k4b_epilogue, dim3(8, BB), dim3(256), 0, stream, x, vbuf, bv, sbuf, gam, out);
}